// Round 1
// baseline (690.296 us; speedup 1.0000x reference)
//
#include <hip/hip_runtime.h>
#include <cstdint>

typedef unsigned short u16;
typedef __attribute__((ext_vector_type(4))) float f32x4;
typedef __attribute__((ext_vector_type(8))) __bf16 bf16x8;
typedef __attribute__((ext_vector_type(8))) u16 u16x8;
typedef __attribute__((ext_vector_type(4))) u16 u16x4;

#define C_OUT 16
#define D_IN 1024
#define HDIM 128
#define NPTS 65536
#define BN 128
#define BK 64

__device__ __forceinline__ u16 f2bf(float f){
  uint32_t u = __builtin_bit_cast(uint32_t, f);
  u += 0x7FFFu + ((u >> 16) & 1u);   // round-to-nearest-even
  return (u16)(u >> 16);
}

__device__ __forceinline__ void gload_lds16(const void* g, void* l){
  __builtin_amdgcn_global_load_lds((const __attribute__((address_space(1))) void*)g,
                                   (__attribute__((address_space(3))) void*)l, 16, 0, 0);
}

// ---------- prep: transpose + fp32->bf16 convert ([ch][R][C] -> [ch][C][R]) ----------
__global__ __launch_bounds__(256) void transpose_cvt(const float* __restrict__ src,
                                                     u16* __restrict__ dst, int R, int C){
  __shared__ float tile[32][33];
  int ch = blockIdx.z;
  int r0 = blockIdx.y * 32, c0 = blockIdx.x * 32;
  const float* s = src + (size_t)ch * R * C;
  u16* d = dst + (size_t)ch * R * C;
  int tx = threadIdx.x, ty = threadIdx.y;
  for (int i = ty; i < 32; i += 8) tile[i][tx] = s[(size_t)(r0 + i) * C + c0 + tx];
  __syncthreads();
  for (int i = ty; i < 32; i += 8) d[(size_t)(c0 + i) * R + r0 + tx] = f2bf(tile[tx][i]);
}

__global__ __launch_bounds__(256) void cvt_x_kernel(const float4* __restrict__ src,
                                                    u16x4* __restrict__ dst, int n4){
  int stride = gridDim.x * 256;
  for (int i = blockIdx.x * 256 + threadIdx.x; i < n4; i += stride){
    float4 v = src[i];
    u16x4 o = { f2bf(v.x), f2bf(v.y), f2bf(v.z), f2bf(v.w) };
    dst[i] = o;
  }
}

// ---------- fused 3-layer MLP, bf16 MFMA ----------
// grid: blockIdx.x = ntile*16 + c  (c-minor so the 16 blocks sharing an x-tile are adjacent)
template<bool XBF16>
__global__ __launch_bounds__(256, 3) void mlp_fused(const void* __restrict__ xsrc,
    const u16* __restrict__ W1T, const u16* __restrict__ W2T,
    const float* __restrict__ b1, const float* __restrict__ b2,
    const float* __restrict__ W3, const float* __restrict__ b3,
    float* __restrict__ out){
  // As(128x64) | Bs(128x64) bf16 = 32 KB; h1s(128x128) aliases the union after layer 1.
  __shared__ __align__(16) u16 smem[2 * BN * BK];
  __shared__ float outb[BN];
  u16* As = smem;
  u16* Bs = smem + BN * BK;

  const int t = threadIdx.x;
  const int wave = t >> 6, lane = t & 63;
  const int q = lane >> 4, s = lane & 15;
  const int wr = (wave >> 1) * 64, wc = (wave & 1) * 64;
  const int c = blockIdx.x & 15;
  const int n0 = (blockIdx.x >> 4) * BN;

  const u16* w1c = W1T + (size_t)c * HDIM * D_IN;

  f32x4 acc[4][4];
#pragma unroll
  for (int i = 0; i < 4; i++)
#pragma unroll
    for (int j = 0; j < 4; j++) acc[i][j] = (f32x4){0.f, 0.f, 0.f, 0.f};

  // ================= layer 1: [128x1024] x [1024x128] =================
  for (int kt = 0; kt < D_IN / BK; kt++){
    // stage B = W1T[c] rows (h-major, k contiguous), xor-swizzled 8-elem chunks
#pragma unroll
    for (int ii = 0; ii < 4; ii++){
      int hbase = wave * 32 + ii * 8;
      int h = hbase + (lane >> 3);
      int k = kt * BK + (((lane & 7) ^ (h & 7)) * 8);
      gload_lds16(w1c + (size_t)h * D_IN + k, &Bs[hbase * BK]);
    }
    // stage A = x tile
    if (XBF16){
      const u16* xb = (const u16*)xsrc;
#pragma unroll
      for (int ii = 0; ii < 4; ii++){
        int rbase = wave * 32 + ii * 8;
        int row = rbase + (lane >> 3);
        int k = kt * BK + (((lane & 7) ^ (row & 7)) * 8);
        gload_lds16(xb + (size_t)(n0 + row) * D_IN + k, &As[rbase * BK]);
      }
    } else {
      const float* xf = (const float*)xsrc;
#pragma unroll
      for (int rr = 0; rr < 4; rr++){
        int row = rr * 32 + (t >> 3);
        const float* srcp = xf + (size_t)(n0 + row) * D_IN + kt * BK + (t & 7) * 8;
        float4 v0 = *(const float4*)srcp;
        float4 v1 = *(const float4*)(srcp + 4);
        u16x8 p = { f2bf(v0.x), f2bf(v0.y), f2bf(v0.z), f2bf(v0.w),
                    f2bf(v1.x), f2bf(v1.y), f2bf(v1.z), f2bf(v1.w) };
        int sc = (t & 7) ^ (row & 7);
        *(u16x8*)&As[row * BK + sc * 8] = p;
      }
    }
    __syncthreads();
#pragma unroll
    for (int ks = 0; ks < 2; ks++){
      bf16x8 a[4], b[4];
#pragma unroll
      for (int i = 0; i < 4; i++){
        int m = wr + i * 16 + s;
        int ch = ks * 4 + q;
        a[i] = __builtin_bit_cast(bf16x8, *(const u16x8*)&As[m * BK + ((ch ^ (m & 7)) * 8)]);
      }
#pragma unroll
      for (int j = 0; j < 4; j++){
        int hh = wc + j * 16 + s;
        int ch = ks * 4 + q;
        b[j] = __builtin_bit_cast(bf16x8, *(const u16x8*)&Bs[hh * BK + ((ch ^ (hh & 7)) * 8)]);
      }
#pragma unroll
      for (int i = 0; i < 4; i++)
#pragma unroll
        for (int j = 0; j < 4; j++)
          acc[i][j] = __builtin_amdgcn_mfma_f32_16x16x32_bf16(a[i], b[j], acc[i][j], 0, 0, 0);
    }
    __syncthreads();
  }

  // ---- layer1 epilogue: bias + relu -> h1s (bf16, swizzled, aliases As/Bs) ----
  float b1v[4];
#pragma unroll
  for (int j = 0; j < 4; j++) b1v[j] = b1[c * HDIM + wc + j * 16 + s];
  u16* h1s = smem; // 128 x 128
#pragma unroll
  for (int i = 0; i < 4; i++)
#pragma unroll
    for (int j = 0; j < 4; j++)
#pragma unroll
      for (int r = 0; r < 4; r++){
        float v = fmaxf(acc[i][j][r] + b1v[j], 0.f);
        int m = wr + i * 16 + q * 4 + r;
        int h = wc + j * 16 + s;
        h1s[m * HDIM + (((h >> 3) ^ (m & 7)) * 8) + (h & 7)] = f2bf(v);
      }
  __syncthreads();

  // ================= layer 2: [128x128] x [128x128], B-frags direct from L2-hot W2T =================
  const u16* w2c = W2T + (size_t)c * HDIM * HDIM;
  f32x4 acc2[4][4];
#pragma unroll
  for (int i = 0; i < 4; i++)
#pragma unroll
    for (int j = 0; j < 4; j++) acc2[i][j] = (f32x4){0.f, 0.f, 0.f, 0.f};
#pragma unroll
  for (int ks = 0; ks < 4; ks++){
    bf16x8 a[4], b[4];
#pragma unroll
    for (int i = 0; i < 4; i++){
      int m = wr + i * 16 + s;
      int ch = ks * 4 + q;
      a[i] = __builtin_bit_cast(bf16x8, *(const u16x8*)&h1s[m * HDIM + ((ch ^ (m & 7)) * 8)]);
    }
#pragma unroll
    for (int j = 0; j < 4; j++){
      int col = wc + j * 16 + s;
      b[j] = __builtin_bit_cast(bf16x8, *(const u16x8*)(w2c + (size_t)col * HDIM + ks * 32 + q * 8));
    }
#pragma unroll
    for (int i = 0; i < 4; i++)
#pragma unroll
      for (int j = 0; j < 4; j++)
        acc2[i][j] = __builtin_amdgcn_mfma_f32_16x16x32_bf16(a[i], b[j], acc2[i][j], 0, 0, 0);
  }

  // ---- layer2 epilogue + layer 3 dot: shuffle-reduce across the 16-lane col group ----
  float b2v[4], w3v[4];
#pragma unroll
  for (int j = 0; j < 4; j++){
    b2v[j] = b2[c * HDIM + wc + j * 16 + s];
    w3v[j] = W3[c * HDIM + wc + j * 16 + s];
  }
  float part[4][4];
#pragma unroll
  for (int i = 0; i < 4; i++)
#pragma unroll
    for (int r = 0; r < 4; r++) part[i][r] = 0.f;
#pragma unroll
  for (int i = 0; i < 4; i++)
#pragma unroll
    for (int j = 0; j < 4; j++)
#pragma unroll
      for (int r = 0; r < 4; r++){
        float hv = fmaxf(acc2[i][j][r] + b2v[j], 0.f);
        part[i][r] = fmaf(hv, w3v[j], part[i][r]);
      }
#pragma unroll
  for (int mask = 1; mask <= 8; mask <<= 1)
#pragma unroll
    for (int i = 0; i < 4; i++)
#pragma unroll
      for (int r = 0; r < 4; r++) part[i][r] += __shfl_xor(part[i][r], mask, 64);

  if (s == 0 && wc == 0){
#pragma unroll
    for (int i = 0; i < 4; i++)
#pragma unroll
      for (int r = 0; r < 4; r++) outb[wr + i * 16 + q * 4 + r] = part[i][r];
  }
  __syncthreads();
  if (s == 0 && wc == 64){
#pragma unroll
    for (int i = 0; i < 4; i++)
#pragma unroll
      for (int r = 0; r < 4; r++) outb[wr + i * 16 + q * 4 + r] += part[i][r];
  }
  __syncthreads();
  if (t < BN) out[(size_t)(n0 + t) * C_OUT + c] = outb[t] + b3[c];
}

// ---------- slow-but-correct fallback (only if ws too small for weights) ----------
__global__ __launch_bounds__(256) void mlp_naive(const float* __restrict__ x,
    const float* __restrict__ W1, const float* __restrict__ b1,
    const float* __restrict__ W2, const float* __restrict__ b2,
    const float* __restrict__ W3, const float* __restrict__ b3,
    float* __restrict__ out){
  __shared__ float xs[16 * D_IN];
  __shared__ float h1[16 * HDIM];
  __shared__ float h2[16 * HDIM];
  int c = blockIdx.x & 15;
  int n0 = (blockIdx.x >> 4) * 16;
  int t = threadIdx.x;
  for (int i = t; i < 16 * D_IN; i += 256) xs[i] = x[(size_t)n0 * D_IN + i];
  __syncthreads();
  int h = t & 127, ng = t >> 7;
  const float* w1c = W1 + (size_t)c * D_IN * HDIM;
  float a1[8];
#pragma unroll
  for (int nn = 0; nn < 8; nn++) a1[nn] = 0.f;
  for (int d = 0; d < D_IN; d++){
    float w = w1c[(size_t)d * HDIM + h];
#pragma unroll
    for (int nn = 0; nn < 8; nn++) a1[nn] = fmaf(xs[(ng * 8 + nn) * D_IN + d], w, a1[nn]);
  }
  float bb = b1[c * HDIM + h];
#pragma unroll
  for (int nn = 0; nn < 8; nn++) h1[(ng * 8 + nn) * HDIM + h] = fmaxf(a1[nn] + bb, 0.f);
  __syncthreads();
  const float* w2c = W2 + (size_t)c * HDIM * HDIM;
  float a2[8];
#pragma unroll
  for (int nn = 0; nn < 8; nn++) a2[nn] = 0.f;
  for (int k = 0; k < HDIM; k++){
    float w = w2c[(size_t)k * HDIM + h];
#pragma unroll
    for (int nn = 0; nn < 8; nn++) a2[nn] = fmaf(h1[(ng * 8 + nn) * HDIM + k], w, a2[nn]);
  }
  bb = b2[c * HDIM + h];
#pragma unroll
  for (int nn = 0; nn < 8; nn++) h2[(ng * 8 + nn) * HDIM + h] = fmaxf(a2[nn] + bb, 0.f);
  __syncthreads();
  if (t < 16){
    float ssum = 0.f;
    for (int hh = 0; hh < HDIM; hh++) ssum = fmaf(h2[t * HDIM + hh], W3[c * HDIM + hh], ssum);
    out[(size_t)(n0 + t) * C_OUT + c] = ssum + b3[c];
  }
}

extern "C" void kernel_launch(void* const* d_in, const int* in_sizes, int n_in,
                              void* d_out, int out_size, void* d_ws, size_t ws_size,
                              hipStream_t stream){
  const float* x  = (const float*)d_in[0];
  const float* W1 = (const float*)d_in[1];
  const float* b1 = (const float*)d_in[2];
  const float* W2 = (const float*)d_in[3];
  const float* b2 = (const float*)d_in[4];
  const float* W3 = (const float*)d_in[5];
  const float* b3 = (const float*)d_in[6];
  float* out = (float*)d_out;

  const size_t W1T_elems = (size_t)C_OUT * HDIM * D_IN;   // 2,097,152
  const size_t W2T_elems = (size_t)C_OUT * HDIM * HDIM;   // 262,144
  const size_t ws_w_bytes = (W1T_elems + W2T_elems) * 2;  // 4,718,592 B
  const size_t xb_bytes   = (size_t)NPTS * D_IN * 2;      // 134,217,728 B

  if (ws_size < ws_w_bytes){
    mlp_naive<<<(NPTS / 16) * C_OUT, 256, 0, stream>>>(x, W1, b1, W2, b2, W3, b3, out);
    return;
  }

  u16* W1T = (u16*)d_ws;
  u16* W2T = W1T + W1T_elems;
  // W1 [c][d][h] -> W1T [c][h][d]; W2 [c][h][j] -> W2T [c][j][h]
  transpose_cvt<<<dim3(HDIM / 32, D_IN / 32, C_OUT), dim3(32, 8), 0, stream>>>(W1, W1T, D_IN, HDIM);
  transpose_cvt<<<dim3(HDIM / 32, HDIM / 32, C_OUT), dim3(32, 8), 0, stream>>>(W2, W2T, HDIM, HDIM);

  const int grid = (NPTS / BN) * C_OUT;  // 8192
  if (ws_size >= ws_w_bytes + xb_bytes){
    u16* xb = W2T + W2T_elems;
    cvt_x_kernel<<<8192, 256, 0, stream>>>((const float4*)x, (u16x4*)xb, NPTS * D_IN / 4);
    mlp_fused<true><<<grid, 256, 0, stream>>>(xb, W1T, W2T, b1, b2, W3, b3, out);
  } else {
    mlp_fused<false><<<grid, 256, 0, stream>>>(x, W1T, W2T, b1, b2, W3, b3, out);
  }
}